// Round 3
// baseline (60626.648 us; speedup 1.0000x reference)
//
#include <hip/hip_runtime.h>
#include <math.h>

#define D   128
#define H   256
#define G4  1024   // 4*H
#define B   64
#define T   2048

__device__ __forceinline__ float fast_sig(float x) {
    return 1.0f / (1.0f + __expf(-x));
}
__device__ __forceinline__ float fast_tanh(float x) {
    float a = __expf(-2.0f * fabsf(x));      // in (0,1], never overflows
    float r = (1.0f - a) / (1.0f + a);
    return copysignf(r, x);
}
__device__ __forceinline__ void fma4(float4& s, float a, const float4 w) {
    s.x = fmaf(a, w.x, s.x);
    s.y = fmaf(a, w.y, s.y);
    s.z = fmaf(a, w.z, s.z);
    s.w = fmaf(a, w.w, s.w);
}

// ---------------------------------------------------------------------------
// x-projection GEMM: xp[t_local][b][4H] = x[b][t0+t_local][:] @ W_ih
// grid = (tn/16) * B blocks, 256 threads. Each block: 16 timesteps of one
// batch element, all 1024 gate columns (4 cols per thread).
// ---------------------------------------------------------------------------
__global__ __launch_bounds__(256) void lstm_xproj(
    const float* __restrict__ x, const float* __restrict__ Wih,
    float* __restrict__ xp, int t0, int tn)
{
    const int bi  = blockIdx.x % B;
    const int tt0 = (blockIdx.x / B) * 16;
    const int tid = threadIdx.x;

    __shared__ float4 xt[16][32];   // [t][k/4] : 16x128 floats

    const float4* src = (const float4*)(x + ((size_t)bi * T + (size_t)(t0 + tt0)) * D);
    #pragma unroll
    for (int r = tid; r < 16 * 32; r += 256) ((float4*)xt)[r] = src[r];
    __syncthreads();

    const float4* W4 = (const float4*)Wih;   // [128][256] float4s
    float4 acc[16];
    #pragma unroll
    for (int tt = 0; tt < 16; ++tt) acc[tt] = make_float4(0.f, 0.f, 0.f, 0.f);

    for (int k0 = 0; k0 < 32; ++k0) {
        const int k = 4 * k0;
        float4 w0 = W4[(k + 0) * 256 + tid];
        float4 w1 = W4[(k + 1) * 256 + tid];
        float4 w2 = W4[(k + 2) * 256 + tid];
        float4 w3 = W4[(k + 3) * 256 + tid];
        #pragma unroll
        for (int tt = 0; tt < 16; ++tt) {
            float4 xv = xt[tt][k0];
            fma4(acc[tt], xv.x, w0);
            fma4(acc[tt], xv.y, w1);
            fma4(acc[tt], xv.z, w2);
            fma4(acc[tt], xv.w, w3);
        }
    }
    #pragma unroll
    for (int tt = 0; tt < 16; ++tt) {
        ((float4*)(xp + ((size_t)(tt0 + tt) * B + bi) * G4))[tid] = acc[tt];
    }
}

// ---------------------------------------------------------------------------
// Sequential LSTM scan, L2-streamed W_hh (sync-free baseline).
// One block per batch element, 1024 threads = 16 waves.
// Thread (c4 = tid>>2, ks = tid&3): partial dot for gate columns 4c4..4c4+3
// over k in [64*ks, 64*ks+64); quad shuffle-reduce; threads <256 apply the
// cell update. W_hh (1 MB fp32) is re-read from L2 every step — this kernel
// exists to MEASURE that stream rate (per-step dur calibrates per-CU L2 BW).
// xp row for step i+1 is prefetched into registers during step i.
// INLINE_X: fold x@W_ih into the step (fallback when d_ws is too small).
// ---------------------------------------------------------------------------
template <bool INLINE_X>
__global__ __launch_bounds__(1024) void lstm_scan(
    const float* __restrict__ x,  const float* __restrict__ xp,
    const float* __restrict__ Wih, const float* __restrict__ Whh,
    const float* __restrict__ bias, const float* __restrict__ Wout,
    const float* __restrict__ bout,
    float* __restrict__ hstate, float* __restrict__ cstate,
    float* __restrict__ out, int t0, int tn)
{
    const int b   = blockIdx.x;
    const int tid = threadIdx.x;
    const int c4  = tid >> 2;
    const int ks  = tid & 3;

    __shared__ float h_lds[H];
    __shared__ float gates[G4];
    __shared__ float xrow[2][D];
    __shared__ float red[4];

    float c_reg = 0.f, bi_ = 0.f, bf_ = 0.f, bg_ = 0.f, bo_ = 0.f, wout = 0.f;
    if (tid < H) {
        if (t0 == 0) {
            h_lds[tid] = 0.f;
            c_reg = 0.f;
        } else {
            h_lds[tid] = hstate[b * H + tid];
            c_reg      = cstate[b * H + tid];
        }
        bi_  = bias[tid];
        bf_  = bias[H + tid];
        bg_  = bias[2 * H + tid];
        bo_  = bias[3 * H + tid];
        wout = Wout[tid];
    }
    if (INLINE_X) {
        if (tid < D / 4) {
            ((float4*)xrow[0])[tid] =
                ((const float4*)(x + ((size_t)b * T + t0) * D))[tid];
        }
    }
    __syncthreads();

    const float4* Whh4 = (const float4*)Whh;   // [256][256] float4s
    const float4* Wih4 = (const float4*)Wih;   // [128][256] float4s
    const float4* h4   = (const float4*)h_lds; // [64]

    // xp prefetch registers (ks==0 lanes only)
    float4 xp_cur = make_float4(0.f, 0.f, 0.f, 0.f);
    float4 xp_nxt = make_float4(0.f, 0.f, 0.f, 0.f);
    if (!INLINE_X && ks == 0)
        xp_cur = ((const float4*)(xp + ((size_t)0 * B + b) * G4))[c4];

    for (int i = 0; i < tn; ++i) {
        float4 s = make_float4(0.f, 0.f, 0.f, 0.f);

        if (!INLINE_X) {
            // issue next step's xp load early; consumed next iteration
            if (ks == 0 && (i + 1) < tn)
                xp_nxt = ((const float4*)(xp + ((size_t)(i + 1) * B + b) * G4))[c4];
            if (ks == 0) s = xp_cur;
        } else {
            const float* xr = xrow[i & 1];
            #pragma unroll 2
            for (int k0 = 0; k0 < 8; ++k0) {
                const int k = 32 * ks + 4 * k0;
                float4 xv = *(const float4*)&xr[k];
                float4 w0 = Wih4[(k + 0) * 256 + c4];
                float4 w1 = Wih4[(k + 1) * 256 + c4];
                float4 w2 = Wih4[(k + 2) * 256 + c4];
                float4 w3 = Wih4[(k + 3) * 256 + c4];
                fma4(s, xv.x, w0);
                fma4(s, xv.y, w1);
                fma4(s, xv.z, w2);
                fma4(s, xv.w, w3);
            }
            if (tid < 32 && (i + 1) < tn) {
                ((float4*)xrow[(i + 1) & 1])[tid] =
                    ((const float4*)(x + ((size_t)b * T + (size_t)(t0 + i + 1)) * D))[tid];
            }
        }

        // ---- h @ W_hh, weights streamed from L2 ----
        #pragma unroll 4
        for (int k0 = 0; k0 < 16; ++k0) {
            const int kb = 16 * ks + k0;      // float4 index into h
            float4 hv = h4[kb];
            const int k = 4 * kb;
            float4 w0 = Whh4[(k + 0) * 256 + c4];
            float4 w1 = Whh4[(k + 1) * 256 + c4];
            float4 w2 = Whh4[(k + 2) * 256 + c4];
            float4 w3 = Whh4[(k + 3) * 256 + c4];
            fma4(s, hv.x, w0);
            fma4(s, hv.y, w1);
            fma4(s, hv.z, w2);
            fma4(s, hv.w, w3);
        }

        // reduce the 4 partial sums of each column quad (lanes ks=0..3)
        s.x += __shfl_xor(s.x, 1); s.x += __shfl_xor(s.x, 2);
        s.y += __shfl_xor(s.y, 1); s.y += __shfl_xor(s.y, 2);
        s.z += __shfl_xor(s.z, 1); s.z += __shfl_xor(s.z, 2);
        s.w += __shfl_xor(s.w, 1); s.w += __shfl_xor(s.w, 2);
        if (ks == 0) ((float4*)gates)[c4] = s;
        __syncthreads();   // gates ready

        if (tid < H) {
            const int j = tid;
            float gi = gates[j]         + bi_;
            float gf = gates[H + j]     + bf_;
            float gg = gates[2 * H + j] + bg_;
            float go = gates[3 * H + j] + bo_;
            c_reg = fast_sig(gf) * c_reg + fast_sig(gi) * fast_tanh(gg);
            float hn = fast_sig(go) * fast_tanh(c_reg);
            h_lds[j] = hn;
        }
        __syncthreads();   // h ready for next step

        xp_cur = xp_nxt;
    }

    if (t0 + tn < T) {
        if (tid < H) {
            hstate[b * H + tid] = h_lds[tid];
            cstate[b * H + tid] = c_reg;
        }
    } else {
        if (tid < H) {
            float p = h_lds[tid] * wout;
            #pragma unroll
            for (int m = 32; m >= 1; m >>= 1) p += __shfl_xor(p, m);
            if ((tid & 63) == 0) red[tid >> 6] = p;
        }
        __syncthreads();
        if (tid == 0) out[b] = red[0] + red[1] + red[2] + red[3] + bout[0];
    }
}

// ---------------------------------------------------------------------------
extern "C" void kernel_launch(void* const* d_in, const int* in_sizes, int n_in,
                              void* d_out, int out_size, void* d_ws, size_t ws_size,
                              hipStream_t stream)
{
    const float* x    = (const float*)d_in[0];
    const float* Wih  = (const float*)d_in[1];
    const float* Whh  = (const float*)d_in[2];
    const float* bias = (const float*)d_in[3];
    const float* Wout = (const float*)d_in[4];
    const float* bout = (const float*)d_in[5];
    float* out = (float*)d_out;

    const size_t state_bytes = (size_t)2 * B * H * sizeof(float);

    // choose largest power-of-two T-chunk whose x_proj buffer fits in d_ws
    int chunkT = 0;
    for (int c = T; c >= 16; c >>= 1) {
        if ((size_t)c * B * G4 * sizeof(float) + state_bytes <= ws_size) {
            chunkT = c;
            break;
        }
    }

    if (chunkT == 0) {
        // workspace too small: fully fused fallback
        lstm_scan<true><<<B, 1024, 0, stream>>>(
            x, nullptr, Wih, Whh, bias, Wout, bout,
            nullptr, nullptr, out, 0, T);
    } else {
        float* xp = (float*)d_ws;
        float* hs = (float*)((char*)d_ws + (size_t)chunkT * B * G4 * sizeof(float));
        float* cs = hs + B * H;
        for (int t0 = 0; t0 < T; t0 += chunkT) {
            lstm_xproj<<<dim3((chunkT / 16) * B), 256, 0, stream>>>(
                x, Wih, xp, t0, chunkT);
            lstm_scan<false><<<B, 1024, 0, stream>>>(
                x, xp, Wih, Whh, bias, Wout, bout,
                hs, cs, out, t0, chunkT);
        }
    }
}